// Round 3
// baseline (1611.871 us; speedup 1.0000x reference)
//
#include <hip/hip_runtime.h>
#include <hip/hip_bf16.h>

// All inputs/outputs are float32 (per the reference file's setup_inputs).

// ---------------------------------------------------------------------------
// 3x3 SAME conv, 64->64 channels, NCHW. Block = one (b,h) row, 256 threads.
// LDS: 3 input rows x 64ci x 64w (48KB). Thread: co = t&63, 16 pixels.
// Optional addsrc (for cb conv: + x1).
// ---------------------------------------------------------------------------
__global__ __launch_bounds__(256) void conv3x3_k(const float* __restrict__ in,
    const float* __restrict__ w, const float* __restrict__ bias,
    const float* __restrict__ addsrc, float* __restrict__ out)
{
    const int bh = blockIdx.x;
    const int b = bh >> 6, h = bh & 63;
    __shared__ float lin[3 * 4096];  // [r][ci][w]
    for (int e = threadIdx.x; e < 3 * 4096; e += 256) {
        const int r = e >> 12, ci = (e >> 6) & 63, ww = e & 63;
        const int hh = h - 1 + r;
        float v = 0.f;
        if (hh >= 0 && hh < 64) v = in[((b * 64 + ci) * 64 + hh) * 64 + ww];
        lin[e] = v;
    }
    __syncthreads();
    const int co = threadIdx.x & 63, pg = threadIdx.x >> 6;
    const int wb = pg * 16;
    float acc[16];
    const float bv = bias[co];
#pragma unroll
    for (int p = 0; p < 16; ++p) acc[p] = bv;
    for (int ci = 0; ci < 64; ++ci) {
        const float* wp = w + (co * 64 + ci) * 9;
#pragma unroll
        for (int r = 0; r < 3; ++r) {
            const float w0 = wp[r * 3 + 0];
            const float w1 = wp[r * 3 + 1];
            const float w2 = wp[r * 3 + 2];
            const float* row = &lin[r * 4096 + ci * 64];
            float vm = (wb > 0) ? row[wb - 1] : 0.f;
            float vc = row[wb];
#pragma unroll
            for (int p = 0; p < 16; ++p) {
                const int wn = wb + p + 1;
                const float vn = (wn < 64) ? row[wn] : 0.f;
                acc[p] = fmaf(w0, vm, acc[p]);
                acc[p] = fmaf(w1, vc, acc[p]);
                acc[p] = fmaf(w2, vn, acc[p]);
                vm = vc; vc = vn;
            }
        }
    }
    float* orow = out + ((b * 64 + co) * 64 + h) * 64 + wb;
    if (addsrc) {
        const float* arow = addsrc + ((b * 64 + co) * 64 + h) * 64 + wb;
#pragma unroll
        for (int p = 0; p < 16; ++p) orow[p] = acc[p] + arow[p];
    } else {
#pragma unroll
        for (int p = 0; p < 16; ++p) orow[p] = acc[p];
    }
}

// ---------------------------------------------------------------------------
// InstanceNorm over HxW per (b,c) + LeakyReLU(0.2). Block per (b,c).
// in != out (no aliasing).
// ---------------------------------------------------------------------------
__global__ __launch_bounds__(256) void inorm_lrelu_k(const float* __restrict__ in,
                                                     float* __restrict__ out)
{
    const int bc = blockIdx.x;
    const float* row = in + (size_t)bc * 4096;
    float s1 = 0.f, s2 = 0.f;
    for (int i = threadIdx.x; i < 4096; i += 256) {
        const float v = row[i];
        s1 += v; s2 = fmaf(v, v, s2);
    }
#pragma unroll
    for (int mk = 1; mk < 64; mk <<= 1) {
        s1 += __shfl_xor(s1, mk, 64);
        s2 += __shfl_xor(s2, mk, 64);
    }
    __shared__ float a1[4], a2[4];
    const int wid = threadIdx.x >> 6;
    if ((threadIdx.x & 63) == 0) { a1[wid] = s1; a2[wid] = s2; }
    __syncthreads();
    const float S1 = a1[0] + a1[1] + a1[2] + a1[3];
    const float S2 = a2[0] + a2[1] + a2[2] + a2[3];
    const float mu = S1 * (1.f / 4096.f);
    const float var = S2 * (1.f / 4096.f) - mu * mu;
    const float rstd = rsqrtf(var + 1e-5f);
    float* orow = out + (size_t)bc * 4096;
    for (int i = threadIdx.x; i < 4096; i += 256) {
        float v = (row[i] - mu) * rstd;
        v = (v >= 0.f) ? v : 0.2f * v;
        orow[i] = v;
    }
}

// ---------------------------------------------------------------------------
// LayerNorm over 64 channels (NHWC view of x1) + in_proj (256x64 GEMM).
// Block = 32 positions, 256 threads. Outputs xin (b,128,L) and z (b,l,128).
// ---------------------------------------------------------------------------
__global__ __launch_bounds__(256) void ln_inproj_k(const float* __restrict__ x1,
    const float* __restrict__ g, const float* __restrict__ be,
    const float* __restrict__ w, float* __restrict__ xin_raw, float* __restrict__ z)
{
    const int bx = blockIdx.x;
    const int b = bx >> 7, l0 = (bx & 127) * 32;
    __shared__ float tile[32 * 65];
    __shared__ float smean[32], srstd[32];
    for (int e = threadIdx.x; e < 2048; e += 256) {
        const int c = e >> 5, j = e & 31;
        tile[j * 65 + c] = x1[(b * 64 + c) * 4096 + l0 + j];
    }
    __syncthreads();
    {
        const int pos = threadIdx.x >> 3, gg = threadIdx.x & 7;
        float s1 = 0.f, s2 = 0.f;
#pragma unroll
        for (int i = 0; i < 8; ++i) {
            const float v = tile[pos * 65 + gg + i * 8];
            s1 += v; s2 = fmaf(v, v, s2);
        }
#pragma unroll
        for (int mk = 1; mk < 8; mk <<= 1) {
            s1 += __shfl_xor(s1, mk, 8);
            s2 += __shfl_xor(s2, mk, 8);
        }
        if (gg == 0) {
            const float mu = s1 * (1.f / 64.f);
            const float var = s2 * (1.f / 64.f) - mu * mu;
            smean[pos] = mu;
            srstd[pos] = rsqrtf(var + 1e-5f);
        }
    }
    __syncthreads();
    for (int e = threadIdx.x; e < 2048; e += 256) {
        const int j = e >> 6, c = e & 63;
        tile[j * 65 + c] = (tile[j * 65 + c] - smean[j]) * srstd[j] * g[c] + be[c];
    }
    __syncthreads();
    {
        const int e = threadIdx.x;  // output channel 0..255
        float acc[32];
#pragma unroll
        for (int j = 0; j < 32; ++j) acc[j] = 0.f;
        for (int c = 0; c < 64; ++c) {
            const float wv = w[e * 64 + c];
#pragma unroll
            for (int j = 0; j < 32; ++j) acc[j] = fmaf(tile[j * 65 + c], wv, acc[j]);
        }
        if (e < 128) {
            float* dst = xin_raw + (b * 128 + e) * 4096 + l0;
#pragma unroll
            for (int j = 0; j < 32; ++j) dst[j] = acc[j];
        } else {
            float* dst = z + ((size_t)(b * 4096 + l0)) * 128 + (e - 128);
#pragma unroll
            for (int j = 0; j < 32; ++j) dst[j * 128] = acc[j];
        }
    }
}

// ---------------------------------------------------------------------------
// Depthwise 3x3 SAME conv + bias + SiLU on (b,128,64,64).
// ---------------------------------------------------------------------------
__global__ __launch_bounds__(256) void dwconv_silu_k(const float* __restrict__ in,
    const float* __restrict__ w, const float* __restrict__ bias, float* __restrict__ out)
{
    const int idx = blockIdx.x * 256 + threadIdx.x;  // (b*128+d)*4096 + l
    const int l = idx & 4095, bd = idx >> 12, d = bd & 127;
    const int hh = l >> 6, ww = l & 63;
    const float* base = in + (size_t)bd * 4096;
    float acc = bias[d];
    const float* wp = w + d * 9;
#pragma unroll
    for (int dy = 0; dy < 3; ++dy) {
        const int y = hh + dy - 1;
        if (y < 0 || y > 63) continue;
#pragma unroll
        for (int dx = 0; dx < 3; ++dx) {
            const int xx = ww + dx - 1;
            if (xx < 0 || xx > 63) continue;
            acc = fmaf(base[y * 64 + xx], wp[dy * 3 + dx], acc);
        }
    }
    out[idx] = acc / (1.f + __expf(-acc));  // silu
}

// ---------------------------------------------------------------------------
// 64x64 spatial transpose per (b,d): xin_T[wi*64+hi] = xin_s[hi*64+wi].
// ---------------------------------------------------------------------------
__global__ __launch_bounds__(256) void transpose_k(const float* __restrict__ in,
                                                   float* __restrict__ out)
{
    const int bd = blockIdx.x;
    __shared__ float tl[64 * 65];
    const float* src = in + (size_t)bd * 4096;
    for (int e = threadIdx.x; e < 4096; e += 256) {
        const int r = e >> 6, c = e & 63;
        tl[r * 65 + c] = src[e];
    }
    __syncthreads();
    float* dst = out + (size_t)bd * 4096;
    for (int e = threadIdx.x; e < 4096; e += 256) {
        const int wi = e >> 6, hi = e & 63;
        dst[e] = tl[hi * 65 + wi];
    }
}

// ---------------------------------------------------------------------------
// x_dbl[b,k,c,m] = sum_d xs[b,k,d,m] * x_proj_w[k,c,d]  (c=36, scan order m)
// Block = 32 scan positions for one (b,k). LDS stages 128x32 xs tile.
// ---------------------------------------------------------------------------
__global__ __launch_bounds__(256) void xdbl_k(const float* __restrict__ xin_s,
    const float* __restrict__ xin_T, const float* __restrict__ xpw,
    float* __restrict__ xdbl)
{
    const int bx = blockIdx.x;
    const int bk = bx >> 7, m0 = (bx & 127) * 32;
    const int b = bk >> 2, k = bk & 3;
    __shared__ float tl[128 * 33];
    const float* src = (k & 1) ? xin_T : xin_s;
    const bool rev = (k >= 2);
    for (int e = threadIdx.x; e < 4096; e += 256) {
        const int d = e >> 5, j = e & 31;
        const int m = m0 + j;
        const int um = rev ? (4095 - m) : m;
        tl[d * 33 + j] = src[(b * 128 + d) * 4096 + um];
    }
    __syncthreads();
    const int j = threadIdx.x & 31, c0 = threadIdx.x >> 5;
    float acc[5] = {0.f, 0.f, 0.f, 0.f, 0.f};
    for (int d = 0; d < 128; ++d) {
        const float v = tl[d * 33 + j];
#pragma unroll
        for (int q = 0; q < 5; ++q) {
            const int c = c0 + q * 8;
            if (c < 36) acc[q] = fmaf(v, xpw[(k * 36 + c) * 128 + d], acc[q]);
        }
    }
#pragma unroll
    for (int q = 0; q < 5; ++q) {
        const int c = c0 + q * 8;
        if (c < 36) xdbl[((size_t)bk * 36 + c) * 4096 + m0 + j] = acc[q];
    }
}

// ---------------------------------------------------------------------------
// Selective scan with inline dt-projection+softplus. Lane layout: n = t&15
// (state dim), chain = t>>4 (16 d-chains per block). Grid = 128 blocks:
// (b,k,d8). h in register; per 128-step chunk, B/C/dt/u staged in LDS
// (pad 129). y reduced over 16 n-lanes via shfl_xor, atomicAdd into
// y_total[b, l_orig, d].
// ---------------------------------------------------------------------------
__global__ __launch_bounds__(256) void scan_k(const float* __restrict__ xdbl,
    const float* __restrict__ xin_s, const float* __restrict__ xin_T,
    const float* __restrict__ A_logs, const float* __restrict__ dtw,
    const float* __restrict__ dtb, float* __restrict__ y_total)
{
    const int bx = blockIdx.x;
    const int b = bx >> 5, k = (bx >> 3) & 3, d8 = bx & 7;
    const int t = threadIdx.x;
    const int chain = t >> 4, n = t & 15;
    const int d = d8 * 16 + chain;
    const int bk = b * 4 + k;
    const float A = -__expf(A_logs[(k * 128 + d) * 16 + n]);
    __shared__ float sB[16 * 129], sC[16 * 129], sdt[16 * 129], su[16 * 129];
    const float* srcu = (k & 1) ? xin_T : xin_s;
    const bool rev = (k >= 2);
    const int jj = t & 127, half = t >> 7;
    float h = 0.f;
    for (int m0 = 0; m0 < 4096; m0 += 128) {
        __syncthreads();
        // stage: each thread handles column jj, rows half, half+2, ... half+14
        const float dts0 = xdbl[((size_t)bk * 36 + 0) * 4096 + m0 + jj];
        const float dts1 = xdbl[((size_t)bk * 36 + 1) * 4096 + m0 + jj];
        const float dts2 = xdbl[((size_t)bk * 36 + 2) * 4096 + m0 + jj];
        const float dts3 = xdbl[((size_t)bk * 36 + 3) * 4096 + m0 + jj];
        const int m = m0 + jj;
        const int um = rev ? (4095 - m) : m;
#pragma unroll
        for (int i = 0; i < 8; ++i) {
            const int nn = half + 2 * i;
            sB[nn * 129 + jj] = xdbl[((size_t)bk * 36 + 4 + nn) * 4096 + m0 + jj];
            sC[nn * 129 + jj] = xdbl[((size_t)bk * 36 + 20 + nn) * 4096 + m0 + jj];
            const int dd = d8 * 16 + nn;
            const float* wp = dtw + (k * 128 + dd) * 4;
            float s = dtb[k * 128 + dd];
            s = fmaf(dts0, wp[0], s);
            s = fmaf(dts1, wp[1], s);
            s = fmaf(dts2, wp[2], s);
            s = fmaf(dts3, wp[3], s);
            sdt[nn * 129 + jj] = (s > 20.f) ? s : log1pf(__expf(s));
            su[nn * 129 + jj] = srcu[(b * 128 + dd) * 4096 + um];
        }
        __syncthreads();
        const float* bB = sB + n * 129;
        const float* bC = sC + n * 129;
        const float* bdt = sdt + chain * 129;
        const float* bu = su + chain * 129;
#pragma unroll 4
        for (int j = 0; j < 128; ++j) {
            const float dt = bdt[j];
            const float u = bu[j];
            const float alpha = __expf(dt * A);
            h = fmaf(h, alpha, dt * u * bB[j]);
            float p = h * bC[j];
            p += __shfl_xor(p, 1, 16);
            p += __shfl_xor(p, 2, 16);
            p += __shfl_xor(p, 4, 16);
            p += __shfl_xor(p, 8, 16);
            if (n == 0) {
                const int mm2 = m0 + j;
                int l;
                if (k == 0) l = mm2;
                else if (k == 1) l = ((mm2 & 63) << 6) | (mm2 >> 6);
                else if (k == 2) l = 4095 - mm2;
                else { const int mf = 4095 - mm2; l = ((mf & 63) << 6) | (mf >> 6); }
                atomicAdd(&y_total[((size_t)b * 4096 + l) * 128 + d], p);
            }
        }
    }
}

// ---------------------------------------------------------------------------
// Finalize: y += (sum_k Ds)*u; LN over 128; * silu(z); out_proj (64x128 GEMV);
// + skip_scale*x1  -> res (NCHW). Block per (b,l), 128 threads.
// ---------------------------------------------------------------------------
__global__ __launch_bounds__(128) void finalize_k(const float* __restrict__ y_total,
    const float* __restrict__ xin_s, const float* __restrict__ z,
    const float* __restrict__ x1, const float* __restrict__ Dsp,
    const float* __restrict__ ong, const float* __restrict__ onb,
    const float* __restrict__ opw, const float* __restrict__ skipp,
    float* __restrict__ res)
{
    const int bi = blockIdx.x;
    const int b = bi >> 12, l = bi & 4095;
    const int d = threadIdx.x;
    const float Dsum = Dsp[d] + Dsp[128 + d] + Dsp[256 + d] + Dsp[384 + d];
    const float u = xin_s[(b * 128 + d) * 4096 + l];
    const float v = y_total[((size_t)b * 4096 + l) * 128 + d] + Dsum * u;
    float s1 = v, s2 = v * v;
#pragma unroll
    for (int mk = 1; mk < 64; mk <<= 1) {
        s1 += __shfl_xor(s1, mk, 64);
        s2 += __shfl_xor(s2, mk, 64);
    }
    __shared__ float r1[2], r2[2];
    __shared__ float yl[128];
    if ((d & 63) == 0) { r1[d >> 6] = s1; r2[d >> 6] = s2; }
    __syncthreads();
    const float S1 = r1[0] + r1[1], S2 = r2[0] + r2[1];
    const float mu = S1 * (1.f / 128.f);
    const float var = S2 * (1.f / 128.f) - mu * mu;
    const float rstd = rsqrtf(var + 1e-5f);
    const float yln = (v - mu) * rstd * ong[d] + onb[d];
    const float zz = z[((size_t)b * 4096 + l) * 128 + d];
    yl[d] = yln * (zz / (1.f + __expf(-zz)));
    __syncthreads();
    if (d < 64) {
        float acc = 0.f;
        const float* wp = opw + d * 128;
        for (int dd = 0; dd < 128; ++dd) acc = fmaf(yl[dd], wp[dd], acc);
        res[(b * 64 + d) * 4096 + l] = acc + skipp[0] * x1[(b * 64 + d) * 4096 + l];
    }
}

// ---------------------------------------------------------------------------
// Workspace layout (floats), total 13,893,632 floats = 53.0 MB:
//   x1     @ 0          (1,048,576)   live: cf-conv .. cb-conv
//   xin_s  @ 1,048,576  (2,097,152)   live: dwconv .. finalize
//   zbuf   @ 3,145,728  (2,097,152)   live: ln_inproj .. finalize
//   xin_T  @ 5,242,880  (2,097,152)   live: transpose .. scan
//   xdbl   @ 7,340,032  (2,359,296)   live: xdbl_k .. scan
//   ytot   @ 9,699,328  (2,097,152)   live: scan .. finalize
//   G      @ 11,796,480 (2,097,152)   scratch, reused 3x
// ---------------------------------------------------------------------------
extern "C" void kernel_launch(void* const* d_in, const int* in_sizes, int n_in,
                              void* d_out, int out_size, void* d_ws, size_t ws_size,
                              hipStream_t stream)
{
    const float* x          = (const float*)d_in[0];
    const float* conv1_w    = (const float*)d_in[1];
    const float* conv1_b    = (const float*)d_in[2];
    const float* conv2_w    = (const float*)d_in[3];
    const float* conv2_b    = (const float*)d_in[4];
    const float* cf_w       = (const float*)d_in[5];
    const float* cf_b       = (const float*)d_in[6];
    const float* ln_g       = (const float*)d_in[7];
    const float* ln_b       = (const float*)d_in[8];
    const float* in_proj_w  = (const float*)d_in[9];
    const float* dw_w       = (const float*)d_in[10];
    const float* dw_b       = (const float*)d_in[11];
    const float* x_proj_w   = (const float*)d_in[12];
    const float* dt_proj_w  = (const float*)d_in[13];
    const float* dt_proj_b  = (const float*)d_in[14];
    const float* A_logs     = (const float*)d_in[15];
    const float* Ds         = (const float*)d_in[16];
    const float* out_norm_g = (const float*)d_in[17];
    const float* out_norm_b = (const float*)d_in[18];
    const float* out_proj_w = (const float*)d_in[19];
    const float* skip_scale = (const float*)d_in[20];
    const float* cb_w       = (const float*)d_in[21];
    const float* cb_b       = (const float*)d_in[22];
    (void)ln_g; (void)ln_b;

    float* ws = (float*)d_ws;
    float* x1    = ws;                 // 1,048,576
    float* xin_s = ws + 1048576;       // 2,097,152
    float* zbuf  = ws + 3145728;       // 2,097,152
    float* xin_T = ws + 5242880;       // 2,097,152
    float* xdbl  = ws + 7340032;       // 2,359,296
    float* ytot  = ws + 9699328;       // 2,097,152
    float* G     = ws + 11796480;      // 2,097,152 scratch
    float* G0 = G;
    float* G1 = G + 1048576;

    hipMemsetAsync(ytot, 0, 2097152 * sizeof(float), stream);

    conv3x3_k<<<256, 256, 0, stream>>>(x, conv1_w, conv1_b, nullptr, G0);
    inorm_lrelu_k<<<256, 256, 0, stream>>>(G0, G1);
    conv3x3_k<<<256, 256, 0, stream>>>(G1, conv2_w, conv2_b, nullptr, G0);
    conv3x3_k<<<256, 256, 0, stream>>>(G0, cf_w, cf_b, nullptr, x1);
    ln_inproj_k<<<512, 256, 0, stream>>>(x1, ln_g, ln_b, in_proj_w, G /*xin_raw*/, zbuf);
    dwconv_silu_k<<<8192, 256, 0, stream>>>(G /*xin_raw*/, dw_w, dw_b, xin_s);
    transpose_k<<<512, 256, 0, stream>>>(xin_s, xin_T);
    xdbl_k<<<2048, 256, 0, stream>>>(xin_s, xin_T, x_proj_w, xdbl);
    scan_k<<<128, 256, 0, stream>>>(xdbl, xin_s, xin_T, A_logs, dt_proj_w, dt_proj_b, ytot);
    finalize_k<<<16384, 128, 0, stream>>>(ytot, xin_s, zbuf, x1, Ds, out_norm_g,
                                          out_norm_b, out_proj_w, skip_scale, G0 /*res*/);
    conv3x3_k<<<256, 256, 0, stream>>>(G0 /*res*/, cb_w, cb_b, x1, G1 /*tmp*/);
    inorm_lrelu_k<<<256, 256, 0, stream>>>(G1 /*tmp*/, (float*)d_out);
}

// Round 4
// 800.274 us; speedup vs baseline: 2.0141x; 2.0141x over previous
//
#include <hip/hip_runtime.h>
#include <hip/hip_bf16.h>

// All inputs/outputs are float32 (per the reference file's setup_inputs).

// ---------------------------------------------------------------------------
// 3x3 SAME conv, 64->64 channels, NCHW. Block = one (b,h) row, 256 threads.
// LDS: 3 input rows x 64ci x 64w (48KB). Thread: co = t&63, 16 pixels.
// Optional addsrc (for cb conv: + x1).
// ---------------------------------------------------------------------------
__global__ __launch_bounds__(256) void conv3x3_k(const float* __restrict__ in,
    const float* __restrict__ w, const float* __restrict__ bias,
    const float* __restrict__ addsrc, float* __restrict__ out)
{
    const int bh = blockIdx.x;
    const int b = bh >> 6, h = bh & 63;
    __shared__ float lin[3 * 4096];  // [r][ci][w]
    for (int e = threadIdx.x; e < 3 * 4096; e += 256) {
        const int r = e >> 12, ci = (e >> 6) & 63, ww = e & 63;
        const int hh = h - 1 + r;
        float v = 0.f;
        if (hh >= 0 && hh < 64) v = in[((b * 64 + ci) * 64 + hh) * 64 + ww];
        lin[e] = v;
    }
    __syncthreads();
    const int co = threadIdx.x & 63, pg = threadIdx.x >> 6;
    const int wb = pg * 16;
    float acc[16];
    const float bv = bias[co];
#pragma unroll
    for (int p = 0; p < 16; ++p) acc[p] = bv;
    for (int ci = 0; ci < 64; ++ci) {
        const float* wp = w + (co * 64 + ci) * 9;
#pragma unroll
        for (int r = 0; r < 3; ++r) {
            const float w0 = wp[r * 3 + 0];
            const float w1 = wp[r * 3 + 1];
            const float w2 = wp[r * 3 + 2];
            const float* row = &lin[r * 4096 + ci * 64];
            float vm = (wb > 0) ? row[wb - 1] : 0.f;
            float vc = row[wb];
#pragma unroll
            for (int p = 0; p < 16; ++p) {
                const int wn = wb + p + 1;
                const float vn = (wn < 64) ? row[wn] : 0.f;
                acc[p] = fmaf(w0, vm, acc[p]);
                acc[p] = fmaf(w1, vc, acc[p]);
                acc[p] = fmaf(w2, vn, acc[p]);
                vm = vc; vc = vn;
            }
        }
    }
    float* orow = out + ((b * 64 + co) * 64 + h) * 64 + wb;
    if (addsrc) {
        const float* arow = addsrc + ((b * 64 + co) * 64 + h) * 64 + wb;
#pragma unroll
        for (int p = 0; p < 16; ++p) orow[p] = acc[p] + arow[p];
    } else {
#pragma unroll
        for (int p = 0; p < 16; ++p) orow[p] = acc[p];
    }
}

// ---------------------------------------------------------------------------
// InstanceNorm over HxW per (b,c) + LeakyReLU(0.2). Block per (b,c).
// ---------------------------------------------------------------------------
__global__ __launch_bounds__(256) void inorm_lrelu_k(const float* __restrict__ in,
                                                     float* __restrict__ out)
{
    const int bc = blockIdx.x;
    const float* row = in + (size_t)bc * 4096;
    float s1 = 0.f, s2 = 0.f;
    for (int i = threadIdx.x; i < 4096; i += 256) {
        const float v = row[i];
        s1 += v; s2 = fmaf(v, v, s2);
    }
#pragma unroll
    for (int mk = 1; mk < 64; mk <<= 1) {
        s1 += __shfl_xor(s1, mk, 64);
        s2 += __shfl_xor(s2, mk, 64);
    }
    __shared__ float a1[4], a2[4];
    const int wid = threadIdx.x >> 6;
    if ((threadIdx.x & 63) == 0) { a1[wid] = s1; a2[wid] = s2; }
    __syncthreads();
    const float S1 = a1[0] + a1[1] + a1[2] + a1[3];
    const float S2 = a2[0] + a2[1] + a2[2] + a2[3];
    const float mu = S1 * (1.f / 4096.f);
    const float var = S2 * (1.f / 4096.f) - mu * mu;
    const float rstd = rsqrtf(var + 1e-5f);
    float* orow = out + (size_t)bc * 4096;
    for (int i = threadIdx.x; i < 4096; i += 256) {
        float v = (row[i] - mu) * rstd;
        v = (v >= 0.f) ? v : 0.2f * v;
        orow[i] = v;
    }
}

// ---------------------------------------------------------------------------
// LayerNorm over 64 channels (NHWC view of x1) + in_proj (256x64 GEMM).
// Block = 32 positions, 256 threads. Outputs xin (b,128,L) and z (b,l,128).
// ---------------------------------------------------------------------------
__global__ __launch_bounds__(256) void ln_inproj_k(const float* __restrict__ x1,
    const float* __restrict__ g, const float* __restrict__ be,
    const float* __restrict__ w, float* __restrict__ xin_raw, float* __restrict__ z)
{
    const int bx = blockIdx.x;
    const int b = bx >> 7, l0 = (bx & 127) * 32;
    __shared__ float tile[32 * 65];
    __shared__ float smean[32], srstd[32];
    for (int e = threadIdx.x; e < 2048; e += 256) {
        const int c = e >> 5, j = e & 31;
        tile[j * 65 + c] = x1[(b * 64 + c) * 4096 + l0 + j];
    }
    __syncthreads();
    {
        const int pos = threadIdx.x >> 3, gg = threadIdx.x & 7;
        float s1 = 0.f, s2 = 0.f;
#pragma unroll
        for (int i = 0; i < 8; ++i) {
            const float v = tile[pos * 65 + gg + i * 8];
            s1 += v; s2 = fmaf(v, v, s2);
        }
#pragma unroll
        for (int mk = 1; mk < 8; mk <<= 1) {
            s1 += __shfl_xor(s1, mk, 8);
            s2 += __shfl_xor(s2, mk, 8);
        }
        if (gg == 0) {
            const float mu = s1 * (1.f / 64.f);
            const float var = s2 * (1.f / 64.f) - mu * mu;
            smean[pos] = mu;
            srstd[pos] = rsqrtf(var + 1e-5f);
        }
    }
    __syncthreads();
    for (int e = threadIdx.x; e < 2048; e += 256) {
        const int j = e >> 6, c = e & 63;
        tile[j * 65 + c] = (tile[j * 65 + c] - smean[j]) * srstd[j] * g[c] + be[c];
    }
    __syncthreads();
    {
        const int e = threadIdx.x;  // output channel 0..255
        float acc[32];
#pragma unroll
        for (int j = 0; j < 32; ++j) acc[j] = 0.f;
        for (int c = 0; c < 64; ++c) {
            const float wv = w[e * 64 + c];
#pragma unroll
            for (int j = 0; j < 32; ++j) acc[j] = fmaf(tile[j * 65 + c], wv, acc[j]);
        }
        if (e < 128) {
            float* dst = xin_raw + (b * 128 + e) * 4096 + l0;
#pragma unroll
            for (int j = 0; j < 32; ++j) dst[j] = acc[j];
        } else {
            float* dst = z + ((size_t)(b * 4096 + l0)) * 128 + (e - 128);
#pragma unroll
            for (int j = 0; j < 32; ++j) dst[j * 128] = acc[j];
        }
    }
}

// ---------------------------------------------------------------------------
// Depthwise 3x3 SAME conv + bias + SiLU on (b,128,64,64).
// ---------------------------------------------------------------------------
__global__ __launch_bounds__(256) void dwconv_silu_k(const float* __restrict__ in,
    const float* __restrict__ w, const float* __restrict__ bias, float* __restrict__ out)
{
    const int idx = blockIdx.x * 256 + threadIdx.x;  // (b*128+d)*4096 + l
    const int l = idx & 4095, bd = idx >> 12, d = bd & 127;
    const int hh = l >> 6, ww = l & 63;
    const float* base = in + (size_t)bd * 4096;
    float acc = bias[d];
    const float* wp = w + d * 9;
#pragma unroll
    for (int dy = 0; dy < 3; ++dy) {
        const int y = hh + dy - 1;
        if (y < 0 || y > 63) continue;
#pragma unroll
        for (int dx = 0; dx < 3; ++dx) {
            const int xx = ww + dx - 1;
            if (xx < 0 || xx > 63) continue;
            acc = fmaf(base[y * 64 + xx], wp[dy * 3 + dx], acc);
        }
    }
    out[idx] = acc / (1.f + __expf(-acc));  // silu
}

// ---------------------------------------------------------------------------
// 64x64 spatial transpose per (b,d): xin_T[wi*64+hi] = xin_s[hi*64+wi].
// ---------------------------------------------------------------------------
__global__ __launch_bounds__(256) void transpose_k(const float* __restrict__ in,
                                                   float* __restrict__ out)
{
    const int bd = blockIdx.x;
    __shared__ float tl[64 * 65];
    const float* src = in + (size_t)bd * 4096;
    for (int e = threadIdx.x; e < 4096; e += 256) {
        const int r = e >> 6, c = e & 63;
        tl[r * 65 + c] = src[e];
    }
    __syncthreads();
    float* dst = out + (size_t)bd * 4096;
    for (int e = threadIdx.x; e < 4096; e += 256) {
        const int wi = e >> 6, hi = e & 63;
        dst[e] = tl[hi * 65 + wi];
    }
}

// ---------------------------------------------------------------------------
// x_dbl[b,k,c,m] = sum_d xs[b,k,d,m] * x_proj_w[k,c,d]  (c=36, scan order m)
// ---------------------------------------------------------------------------
__global__ __launch_bounds__(256) void xdbl_k(const float* __restrict__ xin_s,
    const float* __restrict__ xin_T, const float* __restrict__ xpw,
    float* __restrict__ xdbl)
{
    const int bx = blockIdx.x;
    const int bk = bx >> 7, m0 = (bx & 127) * 32;
    const int b = bk >> 2, k = bk & 3;
    __shared__ float tl[128 * 33];
    const float* src = (k & 1) ? xin_T : xin_s;
    const bool rev = (k >= 2);
    for (int e = threadIdx.x; e < 4096; e += 256) {
        const int d = e >> 5, j = e & 31;
        const int m = m0 + j;
        const int um = rev ? (4095 - m) : m;
        tl[d * 33 + j] = src[(b * 128 + d) * 4096 + um];
    }
    __syncthreads();
    const int j = threadIdx.x & 31, c0 = threadIdx.x >> 5;
    float acc[5] = {0.f, 0.f, 0.f, 0.f, 0.f};
    for (int d = 0; d < 128; ++d) {
        const float v = tl[d * 33 + j];
#pragma unroll
        for (int q = 0; q < 5; ++q) {
            const int c = c0 + q * 8;
            if (c < 36) acc[q] = fmaf(v, xpw[(k * 36 + c) * 128 + d], acc[q]);
        }
    }
#pragma unroll
    for (int q = 0; q < 5; ++q) {
        const int c = c0 + q * 8;
        if (c < 36) xdbl[((size_t)bk * 36 + c) * 4096 + m0 + j] = acc[q];
    }
}

// ---------------------------------------------------------------------------
// Segmented selective scan, phase 1. The recurrence h_t = a_t*h_{t-1} + b_t is
// linear-diagonal, so each 128-step segment computes (zero-start h_end, prod a)
// per (chain, n). Grid: ((bk*8 + d8)*32 + seg) = 4096 blocks, 256 threads
// = 16 chains x 16 n. No shfl, no atomics.
// ---------------------------------------------------------------------------
__global__ __launch_bounds__(256) void scan_p1_k(const float* __restrict__ xdbl,
    const float* __restrict__ xin_s, const float* __restrict__ xin_T,
    const float* __restrict__ A_logs, const float* __restrict__ dtw,
    const float* __restrict__ dtb, float* __restrict__ hseg,
    float* __restrict__ pseg)
{
    const int bx = blockIdx.x;
    const int seg = bx & 31, d8 = (bx >> 5) & 7, bk = bx >> 8;
    const int b = bk >> 2, k = bk & 3;
    const int t = threadIdx.x;
    const int chain = t >> 4, n = t & 15;
    const int d = d8 * 16 + chain;
    const float A = -__expf(A_logs[(k * 128 + d) * 16 + n]);
    __shared__ float sB[16 * 129], sdt[16 * 129], su[16 * 129];
    const float* srcu = (k & 1) ? xin_T : xin_s;
    const bool rev = (k >= 2);
    const int jj = t & 127, half = t >> 7;
    const int m0 = seg * 128;
    {
        const float dts0 = xdbl[((size_t)bk * 36 + 0) * 4096 + m0 + jj];
        const float dts1 = xdbl[((size_t)bk * 36 + 1) * 4096 + m0 + jj];
        const float dts2 = xdbl[((size_t)bk * 36 + 2) * 4096 + m0 + jj];
        const float dts3 = xdbl[((size_t)bk * 36 + 3) * 4096 + m0 + jj];
        const int m = m0 + jj;
        const int um = rev ? (4095 - m) : m;
#pragma unroll
        for (int i = 0; i < 8; ++i) {
            const int nn = half + 2 * i;
            sB[nn * 129 + jj] = xdbl[((size_t)bk * 36 + 4 + nn) * 4096 + m0 + jj];
            const int dd = d8 * 16 + nn;
            const float* wp = dtw + (k * 128 + dd) * 4;
            float s = dtb[k * 128 + dd];
            s = fmaf(dts0, wp[0], s);
            s = fmaf(dts1, wp[1], s);
            s = fmaf(dts2, wp[2], s);
            s = fmaf(dts3, wp[3], s);
            sdt[nn * 129 + jj] = (s > 20.f) ? s : log1pf(__expf(s));
            su[nn * 129 + jj] = srcu[(b * 128 + dd) * 4096 + um];
        }
    }
    __syncthreads();
    const float* bB = sB + n * 129;
    const float* bdt = sdt + chain * 129;
    const float* bu = su + chain * 129;
    float h = 0.f, pr = 1.f;
#pragma unroll 4
    for (int j = 0; j < 128; ++j) {
        const float dt = bdt[j];
        const float alpha = __expf(dt * A);
        h = fmaf(h, alpha, dt * bu[j] * bB[j]);
        pr *= alpha;
    }
    const size_t idx = ((size_t)(bk * 128 + d) * 16 + n) * 32 + seg;
    hseg[idx] = h;
    pseg[idx] = pr;
}

// ---------------------------------------------------------------------------
// Combine segment summaries sequentially (32 per chain-state). In place:
// pseg[seg] is read (propagator), then overwritten with h_start[seg].
// One thread per (bk,d,n) = 32768 threads.
// ---------------------------------------------------------------------------
__global__ __launch_bounds__(256) void scan_combine_k(const float* __restrict__ hseg,
                                                      float* __restrict__ pseg)
{
    const int i = blockIdx.x * 256 + threadIdx.x;  // 0..32767
    const float* hs = hseg + (size_t)i * 32;
    float* ps = pseg + (size_t)i * 32;
    float h = 0.f;
#pragma unroll 4
    for (int s = 0; s < 32; ++s) {
        const float p = ps[s];
        const float he = hs[s];
        ps[s] = h;             // h_start for segment s
        h = fmaf(h, p, he);    // h_end of segment s (exact recurrence on summaries)
    }
}

// ---------------------------------------------------------------------------
// Segmented scan, phase 2: re-run the exact recurrence within each segment
// seeded with h_start (pseg after combine); emit y via 16-lane shfl reduction
// + atomicAdd into y_total[b, l_orig, d]. Grid: 4096 blocks as phase 1.
// ---------------------------------------------------------------------------
__global__ __launch_bounds__(256) void scan_p2_k(const float* __restrict__ xdbl,
    const float* __restrict__ xin_s, const float* __restrict__ xin_T,
    const float* __restrict__ A_logs, const float* __restrict__ dtw,
    const float* __restrict__ dtb, const float* __restrict__ hstart,
    float* __restrict__ y_total)
{
    const int bx = blockIdx.x;
    const int seg = bx & 31, d8 = (bx >> 5) & 7, bk = bx >> 8;
    const int b = bk >> 2, k = bk & 3;
    const int t = threadIdx.x;
    const int chain = t >> 4, n = t & 15;
    const int d = d8 * 16 + chain;
    const float A = -__expf(A_logs[(k * 128 + d) * 16 + n]);
    __shared__ float sB[16 * 129], sC[16 * 129], sdt[16 * 129], su[16 * 129];
    const float* srcu = (k & 1) ? xin_T : xin_s;
    const bool rev = (k >= 2);
    const int jj = t & 127, half = t >> 7;
    const int m0 = seg * 128;
    {
        const float dts0 = xdbl[((size_t)bk * 36 + 0) * 4096 + m0 + jj];
        const float dts1 = xdbl[((size_t)bk * 36 + 1) * 4096 + m0 + jj];
        const float dts2 = xdbl[((size_t)bk * 36 + 2) * 4096 + m0 + jj];
        const float dts3 = xdbl[((size_t)bk * 36 + 3) * 4096 + m0 + jj];
        const int m = m0 + jj;
        const int um = rev ? (4095 - m) : m;
#pragma unroll
        for (int i = 0; i < 8; ++i) {
            const int nn = half + 2 * i;
            sB[nn * 129 + jj] = xdbl[((size_t)bk * 36 + 4 + nn) * 4096 + m0 + jj];
            sC[nn * 129 + jj] = xdbl[((size_t)bk * 36 + 20 + nn) * 4096 + m0 + jj];
            const int dd = d8 * 16 + nn;
            const float* wp = dtw + (k * 128 + dd) * 4;
            float s = dtb[k * 128 + dd];
            s = fmaf(dts0, wp[0], s);
            s = fmaf(dts1, wp[1], s);
            s = fmaf(dts2, wp[2], s);
            s = fmaf(dts3, wp[3], s);
            sdt[nn * 129 + jj] = (s > 20.f) ? s : log1pf(__expf(s));
            su[nn * 129 + jj] = srcu[(b * 128 + dd) * 4096 + um];
        }
    }
    __syncthreads();
    const float* bB = sB + n * 129;
    const float* bC = sC + n * 129;
    const float* bdt = sdt + chain * 129;
    const float* bu = su + chain * 129;
    float h = hstart[((size_t)(bk * 128 + d) * 16 + n) * 32 + seg];
#pragma unroll 4
    for (int j = 0; j < 128; ++j) {
        const float dt = bdt[j];
        const float alpha = __expf(dt * A);
        h = fmaf(h, alpha, dt * bu[j] * bB[j]);
        float p = h * bC[j];
        p += __shfl_xor(p, 1, 16);
        p += __shfl_xor(p, 2, 16);
        p += __shfl_xor(p, 4, 16);
        p += __shfl_xor(p, 8, 16);
        if (n == 0) {
            const int mm2 = m0 + j;
            int l;
            if (k == 0) l = mm2;
            else if (k == 1) l = ((mm2 & 63) << 6) | (mm2 >> 6);
            else if (k == 2) l = 4095 - mm2;
            else { const int mf = 4095 - mm2; l = ((mf & 63) << 6) | (mf >> 6); }
            atomicAdd(&y_total[((size_t)b * 4096 + l) * 128 + d], p);
        }
    }
}

// ---------------------------------------------------------------------------
// Finalize: y += (sum_k Ds)*u; LN over 128; * silu(z); out_proj (64x128 GEMV);
// + skip_scale*x1  -> res (NCHW). Block per (b,l), 128 threads.
// ---------------------------------------------------------------------------
__global__ __launch_bounds__(128) void finalize_k(const float* __restrict__ y_total,
    const float* __restrict__ xin_s, const float* __restrict__ z,
    const float* __restrict__ x1, const float* __restrict__ Dsp,
    const float* __restrict__ ong, const float* __restrict__ onb,
    const float* __restrict__ opw, const float* __restrict__ skipp,
    float* __restrict__ res)
{
    const int bi = blockIdx.x;
    const int b = bi >> 12, l = bi & 4095;
    const int d = threadIdx.x;
    const float Dsum = Dsp[d] + Dsp[128 + d] + Dsp[256 + d] + Dsp[384 + d];
    const float u = xin_s[(b * 128 + d) * 4096 + l];
    const float v = y_total[((size_t)b * 4096 + l) * 128 + d] + Dsum * u;
    float s1 = v, s2 = v * v;
#pragma unroll
    for (int mk = 1; mk < 64; mk <<= 1) {
        s1 += __shfl_xor(s1, mk, 64);
        s2 += __shfl_xor(s2, mk, 64);
    }
    __shared__ float r1[2], r2[2];
    __shared__ float yl[128];
    if ((d & 63) == 0) { r1[d >> 6] = s1; r2[d >> 6] = s2; }
    __syncthreads();
    const float S1 = r1[0] + r1[1], S2 = r2[0] + r2[1];
    const float mu = S1 * (1.f / 128.f);
    const float var = S2 * (1.f / 128.f) - mu * mu;
    const float rstd = rsqrtf(var + 1e-5f);
    const float yln = (v - mu) * rstd * ong[d] + onb[d];
    const float zz = z[((size_t)b * 4096 + l) * 128 + d];
    yl[d] = yln * (zz / (1.f + __expf(-zz)));
    __syncthreads();
    if (d < 64) {
        float acc = 0.f;
        const float* wp = opw + d * 128;
        for (int dd = 0; dd < 128; ++dd) acc = fmaf(yl[dd], wp[dd], acc);
        res[(b * 64 + d) * 4096 + l] = acc + skipp[0] * x1[(b * 64 + d) * 4096 + l];
    }
}

// ---------------------------------------------------------------------------
// Workspace layout (floats), total 13,893,632 floats = 53.0 MB:
//   x1     @ 0          (1,048,576)   live: cf-conv .. cb-conv
//   xin_s  @ 1,048,576  (2,097,152)   live: dwconv .. finalize
//   zbuf   @ 3,145,728  (2,097,152)   live: ln_inproj .. finalize
//   xin_T  @ 5,242,880  (2,097,152)   live: transpose .. scan p2
//   xdbl   @ 7,340,032  (2,359,296)   live: xdbl_k .. scan p2
//   ytot   @ 9,699,328  (2,097,152)   live: scan p2 .. finalize
//   G      @ 11,796,480 (2,097,152)   scratch, reused:
//     conv chain (G0/G1), xin_raw (full G),
//     hseg=G0 / pseg->hstart=G1 during scan,
//     res=G0 / tmp=G1 after finalize
// ---------------------------------------------------------------------------
extern "C" void kernel_launch(void* const* d_in, const int* in_sizes, int n_in,
                              void* d_out, int out_size, void* d_ws, size_t ws_size,
                              hipStream_t stream)
{
    const float* x          = (const float*)d_in[0];
    const float* conv1_w    = (const float*)d_in[1];
    const float* conv1_b    = (const float*)d_in[2];
    const float* conv2_w    = (const float*)d_in[3];
    const float* conv2_b    = (const float*)d_in[4];
    const float* cf_w       = (const float*)d_in[5];
    const float* cf_b       = (const float*)d_in[6];
    const float* ln_g       = (const float*)d_in[7];
    const float* ln_b       = (const float*)d_in[8];
    const float* in_proj_w  = (const float*)d_in[9];
    const float* dw_w       = (const float*)d_in[10];
    const float* dw_b       = (const float*)d_in[11];
    const float* x_proj_w   = (const float*)d_in[12];
    const float* dt_proj_w  = (const float*)d_in[13];
    const float* dt_proj_b  = (const float*)d_in[14];
    const float* A_logs     = (const float*)d_in[15];
    const float* Ds         = (const float*)d_in[16];
    const float* out_norm_g = (const float*)d_in[17];
    const float* out_norm_b = (const float*)d_in[18];
    const float* out_proj_w = (const float*)d_in[19];
    const float* skip_scale = (const float*)d_in[20];
    const float* cb_w       = (const float*)d_in[21];
    const float* cb_b       = (const float*)d_in[22];

    float* ws = (float*)d_ws;
    float* x1    = ws;                 // 1,048,576
    float* xin_s = ws + 1048576;       // 2,097,152
    float* zbuf  = ws + 3145728;       // 2,097,152
    float* xin_T = ws + 5242880;       // 2,097,152
    float* xdbl  = ws + 7340032;       // 2,359,296
    float* ytot  = ws + 9699328;       // 2,097,152
    float* G     = ws + 11796480;      // 2,097,152 scratch
    float* G0 = G;
    float* G1 = G + 1048576;

    hipMemsetAsync(ytot, 0, 2097152 * sizeof(float), stream);

    conv3x3_k<<<256, 256, 0, stream>>>(x, conv1_w, conv1_b, nullptr, G0);
    inorm_lrelu_k<<<256, 256, 0, stream>>>(G0, G1);
    conv3x3_k<<<256, 256, 0, stream>>>(G1, conv2_w, conv2_b, nullptr, G0);
    conv3x3_k<<<256, 256, 0, stream>>>(G0, cf_w, cf_b, nullptr, x1);
    ln_inproj_k<<<512, 256, 0, stream>>>(x1, ln_g, ln_b, in_proj_w, G /*xin_raw*/, zbuf);
    dwconv_silu_k<<<8192, 256, 0, stream>>>(G /*xin_raw*/, dw_w, dw_b, xin_s);
    transpose_k<<<512, 256, 0, stream>>>(xin_s, xin_T);
    xdbl_k<<<2048, 256, 0, stream>>>(xin_s, xin_T, x_proj_w, xdbl);
    // segmented scan: G is free again (xin_raw dead after dwconv)
    scan_p1_k<<<4096, 256, 0, stream>>>(xdbl, xin_s, xin_T, A_logs, dt_proj_w,
                                        dt_proj_b, G0 /*hseg*/, G1 /*pseg*/);
    scan_combine_k<<<128, 256, 0, stream>>>(G0 /*hseg*/, G1 /*pseg->hstart*/);
    scan_p2_k<<<4096, 256, 0, stream>>>(xdbl, xin_s, xin_T, A_logs, dt_proj_w,
                                        dt_proj_b, G1 /*hstart*/, ytot);
    finalize_k<<<16384, 128, 0, stream>>>(ytot, xin_s, zbuf, x1, Ds, out_norm_g,
                                          out_norm_b, out_proj_w, skip_scale, G0 /*res*/);
    conv3x3_k<<<256, 256, 0, stream>>>(G0 /*res*/, cb_w, cb_b, x1, G1 /*tmp*/);
    inorm_lrelu_k<<<256, 256, 0, stream>>>(G1 /*tmp*/, (float*)d_out);
}